// Round 1
// baseline (76.824 us; speedup 1.0000x reference)
//
#include <hip/hip_runtime.h>

// CategoryDense: out[b,c,o] = sum_i x[b,c,i] * kernel[c,i,o] + bias[c,o]
// B=8192, C=64, IN=64, OUT=64, all fp32.

constexpr int C_   = 64;
constexpr int IN_  = 64;
constexpr int OUT_ = 64;
constexpr int BT   = 256;   // batch tile per block
constexpr int KC   = 32;    // K staging chunk

__global__ __launch_bounds__(256)
void cat_dense_f32(const float* __restrict__ x,
                   const float* __restrict__ k,
                   const float* __restrict__ bias,
                   float* __restrict__ out,
                   int B) {
    __shared__ float xs[KC][BT];     // 32 KB, transposed: xs[i][b]
    __shared__ float ks[IN_][OUT_];  // 16 KB

    const int tid  = threadIdx.x;
    const int c    = blockIdx.x & 63;        // category
    const int tile = blockIdx.x >> 6;        // batch tile index
    const long bBase = (long)tile * BT;

    const int to = tid & 7;    // owns outputs [to*8, to*8+8)
    const int tb = tid >> 3;   // owns batches [tb*8, tb*8+8) within tile

    // stage kernel[c] : 4096 floats = 1024 float4, 4 per thread
    {
        const float4* kp = (const float4*)(k + (size_t)c * IN_ * OUT_);
        float4* kd = (float4*)&ks[0][0];
        #pragma unroll
        for (int it = 0; it < 4; ++it) kd[tid + it * 256] = kp[tid + it * 256];
    }

    float acc[8][8];
    #pragma unroll
    for (int r = 0; r < 8; ++r)
        #pragma unroll
        for (int q = 0; q < 8; ++q) acc[r][q] = 0.f;

    for (int kk = 0; kk < IN_; kk += KC) {
        __syncthreads();   // previous chunk fully consumed; ks staged before 1st FMA
        // stage x chunk: BT x KC floats = 2048 float4, 8 per thread (transpose into xs)
        #pragma unroll
        for (int it = 0; it < 8; ++it) {
            int flat = tid + it * 256;        // 0..2047
            int b    = flat >> 3;             // 0..255
            int i0   = (flat & 7) << 2;       // 0,4,..,28
            float4 v = *(const float4*)(x + (size_t)(bBase + b) * (C_ * IN_)
                                          + (size_t)c * IN_ + kk + i0);
            xs[i0 + 0][b] = v.x;
            xs[i0 + 1][b] = v.y;
            xs[i0 + 2][b] = v.z;
            xs[i0 + 3][b] = v.w;
        }
        __syncthreads();

        #pragma unroll
        for (int i = 0; i < KC; ++i) {
            float4 xa = *(const float4*)(&xs[i][tb * 8 + 0]);
            float4 xb = *(const float4*)(&xs[i][tb * 8 + 4]);
            float4 ka = *(const float4*)(&ks[kk + i][to * 8 + 0]);
            float4 kb = *(const float4*)(&ks[kk + i][to * 8 + 4]);
            float xv[8] = {xa.x, xa.y, xa.z, xa.w, xb.x, xb.y, xb.z, xb.w};
            float kv[8] = {ka.x, ka.y, ka.z, ka.w, kb.x, kb.y, kb.z, kb.w};
            #pragma unroll
            for (int r = 0; r < 8; ++r)
                #pragma unroll
                for (int q = 0; q < 8; ++q)
                    acc[r][q] += xv[r] * kv[q];
        }
    }

    // bias + epilogue store
    float bv[8];
    {
        const float* bp = bias + (size_t)c * OUT_ + to * 8;
        #pragma unroll
        for (int q = 0; q < 8; ++q) bv[q] = bp[q];
    }
    #pragma unroll
    for (int r = 0; r < 8; ++r) {
        size_t ob = (size_t)(bBase + tb * 8 + r) * (C_ * OUT_)
                  + (size_t)c * OUT_ + to * 8;
        float4 o0 = make_float4(acc[r][0] + bv[0], acc[r][1] + bv[1],
                                acc[r][2] + bv[2], acc[r][3] + bv[3]);
        float4 o1 = make_float4(acc[r][4] + bv[4], acc[r][5] + bv[5],
                                acc[r][6] + bv[6], acc[r][7] + bv[7]);
        *(float4*)(out + ob)     = o0;
        *(float4*)(out + ob + 4) = o1;
    }
}

extern "C" void kernel_launch(void* const* d_in, const int* in_sizes, int n_in,
                              void* d_out, int out_size, void* d_ws, size_t ws_size,
                              hipStream_t stream) {
    const float* x    = (const float*)d_in[0];
    const float* k    = (const float*)d_in[1];
    const float* bias = (const float*)d_in[2];
    float* out        = (float*)d_out;

    const int B     = in_sizes[0] / (C_ * IN_);   // 8192
    const int tiles = B / BT;                     // 32
    dim3 grid(64 * tiles);                        // 2048 blocks: c = blk & 63
    cat_dense_f32<<<grid, 256, 0, stream>>>(x, k, bias, out, B);
}